// Round 25
// baseline (935.837 us; speedup 1.0000x reference)
//
#include <hip/hip_runtime.h>
#include <hip/hip_fp16.h>

#define N_NODES 50000
#define N_EDGES 800000
#define D 128
#define ED 64
#define NLAYERS 3

typedef __attribute__((ext_vector_type(8))) short s16x8;
typedef __attribute__((ext_vector_type(4))) float f32x4;
#define MFMA16 __builtin_amdgcn_mfma_f32_16x16x32_bf16

__device__ __forceinline__ unsigned short f2bf(float f) {
    unsigned int u = __float_as_uint(f);
    unsigned int r = (u + 0x7FFFu + ((u >> 16) & 1u)) >> 16;
    return (unsigned short)r;
}
__device__ __forceinline__ float bf2f(unsigned short h) {
    return __uint_as_float(((unsigned int)h) << 16);
}

// ---------------- prep kernels ----------------

__global__ void hist_kernel(const int* __restrict__ dst, int* __restrict__ deg) {
    int e = blockIdx.x * blockDim.x + threadIdx.x;
    if (e < N_EDGES) atomicAdd(&deg[dst[e]], 1);
}

// parallel exclusive scan of deg -> cursor (3 phases)
#define SCAN_NB ((N_NODES + 255) / 256)   // 196

__global__ void scan1_kernel(const int* __restrict__ deg, int* __restrict__ curs,
                             int* __restrict__ bsum) {
    __shared__ int wtot[4];
    const int i = blockIdx.x * 256 + threadIdx.x;
    const int l = threadIdx.x & 63, w = threadIdx.x >> 6;
    int v = (i < N_NODES) ? deg[i] : 0;
    int s = v;
    #pragma unroll
    for (int off = 1; off < 64; off <<= 1) {
        int y = __shfl_up(s, off);
        if (l >= off) s += y;
    }
    if (l == 63) wtot[w] = s;
    __syncthreads();
    int add = 0;
    #pragma unroll
    for (int ww = 0; ww < 4; ++ww) if (ww < w) add += wtot[ww];
    if (i < N_NODES) curs[i] = add + s - v;
    if (threadIdx.x == 255) bsum[blockIdx.x] = add + s;
}

__global__ void scan2_kernel(int* __restrict__ bsum) {   // 1 block, 64 threads
    const int l = threadIdx.x;
    int acc = 0;
    for (int base = 0; base < SCAN_NB; base += 64) {
        int v = (base + l < SCAN_NB) ? bsum[base + l] : 0;
        int s = v;
        #pragma unroll
        for (int off = 1; off < 64; off <<= 1) {
            int y = __shfl_up(s, off);
            if (l >= off) s += y;
        }
        if (base + l < SCAN_NB) bsum[base + l] = acc + s - v;
        acc += __shfl(s, 63);
    }
}

__global__ void scan3_kernel(int* __restrict__ curs, const int* __restrict__ bsum) {
    int i = blockIdx.x * 256 + threadIdx.x;
    if (i < N_NODES) curs[i] += bsum[blockIdx.x];
}

// FUSED scatter+reorder: sequential ea read, bf16-hi convert, random write at
// sorted position (atomic cursor). A-lo dropped (r21-validated).
__global__ void reorder_fused_kernel(const float4* __restrict__ ea,
                                     const int* __restrict__ src, const int* __restrict__ dst,
                                     int* __restrict__ cursor,
                                     unsigned short* __restrict__ eahi,
                                     int* __restrict__ srcd, int* __restrict__ dstd) {
    int idx = blockIdx.x * blockDim.x + threadIdx.x;
    int i = idx >> 2, q = idx & 3;     // 4 lanes per edge
    if (i >= N_EDGES) return;
    const int l = threadIdx.x & 63;
    int pos = 0;
    if (q == 0) pos = atomicAdd(&cursor[dst[i]], 1);
    pos = __shfl(pos, (l >> 2) << 2);

    const float4* srow = ea + (size_t)i * (ED / 4) + q * 4;
    float f[16];
    #pragma unroll
    for (int j = 0; j < 4; ++j) {
        float4 v = srow[j];
        f[j * 4 + 0] = v.x; f[j * 4 + 1] = v.y; f[j * 4 + 2] = v.z; f[j * 4 + 3] = v.w;
    }
    s16x8 h0, h1;
    #pragma unroll
    for (int j = 0; j < 8; ++j) h0[j] = (short)f2bf(f[j]);
    #pragma unroll
    for (int j = 0; j < 8; ++j) h1[j] = (short)f2bf(f[8 + j]);
    size_t o = (size_t)pos * ED + q * 16;
    *(s16x8*)&eahi[o] = h0; *(s16x8*)&eahi[o + 8] = h1;
    if (q == 0) { srcd[pos] = src[i]; dstd[pos] = dst[i]; }
}

// Wsrc[L][K][C] -> transposed bf16 hi/lo T[L][C][K]
__global__ void wconvT_kernel(const float* __restrict__ Wsrc,
                              unsigned short* __restrict__ Thi,
                              unsigned short* __restrict__ Tlo,
                              int L, int K, int C) {
    int idx = blockIdx.x * 256 + threadIdx.x;
    if (idx < L * K * C) {
        int l = idx / (K * C);
        int rem = idx % (K * C);
        int k = rem / C, c = rem % C;
        float f = Wsrc[idx];
        unsigned short h = f2bf(f);
        unsigned short lo = f2bf(f - bf2f(h));
        int o = (l * C + c) * K + k;
        Thi[o] = h; Tlo[o] = lo;
    }
}

// seed: P = x (fp32 copy) and xbf = bf16(x), one read pass
__global__ void seed_kernel(const float* __restrict__ xin, float* __restrict__ P,
                            unsigned short* __restrict__ xbf) {
    int idx = blockIdx.x * 256 + threadIdx.x;   // 8 elems per thread
    if (idx < N_NODES * D / 8) {
        const float4* s = (const float4*)xin + (size_t)idx * 2;
        float4 a = s[0], b = s[1];
        float4* p = (float4*)P + (size_t)idx * 2;
        p[0] = a; p[1] = b;
        float f[8] = {a.x, a.y, a.z, a.w, b.x, b.y, b.z, b.w};
        s16x8 h;
        #pragma unroll
        for (int j = 0; j < 8; ++j) h[j] = (short)f2bf(f[j]);
        *(s16x8*)&xbf[(size_t)idx * 8] = h;
    }
}

// ---------------- fused edge pass: 64-edge tiles, 8 blocks/CU ----------------
// 64 dst-sorted edges/block, 4 waves x 16 rows, LDS 16 KB (msg [64][128] fp16;
// 8 KB staging aliased) -> wave-slot-capped 8 blocks/CU. Wave-local staging
// (no stage barrier); barrier A (sM alias) + barrier B (r17, pre-epilogue).
// Half the per-block serial chain of the 128-edge version.

#define GGRID (N_EDGES / 64)       // 12500
#define XQ (GGRID / 8)             // 1562
#define XR (GGRID % 8)             // 4

template<int DIRECT>
__global__ __launch_bounds__(256, 8)
void edge_fused_kernel(const unsigned short* __restrict__ xbf,
                       const unsigned short* __restrict__ eahi,
                       const int* __restrict__ srcd,
                       const int* __restrict__ dstd,
                       const unsigned short* __restrict__ WThi,
                       const unsigned short* __restrict__ WTlo,
                       const float* __restrict__ be,
                       float* __restrict__ hpre)
{
    __shared__ __half sM[64 * 128];                  // 16384 B (msg tile, swizzled)
    unsigned short* sAhi = (unsigned short*)sM;      // 8 KB staging aliased at base

    const int t = threadIdx.x;
    const int bid = blockIdx.x;
    const int xcd = bid & 7, jj = bid >> 3;
    const int blk = (xcd < XR ? xcd * (XQ + 1) : XR * (XQ + 1) + (xcd - XR) * XQ) + jj;
    const int e0 = blk * 64;

    // ---- stage (hi only; wave-local rows: wave w stages edges [16w,16w+16)) ----
    {
        const int el = t >> 2, k0 = (t & 3) * 16;
        const int swz = (el & 7) << 3;
        const size_t gb = (size_t)(e0 + el) * ED + k0;
        *(s16x8*)&sAhi[(el * ED + k0 + 0) ^ swz] = *(const s16x8*)&eahi[gb + 0];
        *(s16x8*)&sAhi[(el * ED + k0 + 8) ^ swz] = *(const s16x8*)&eahi[gb + 8];
    }

    const int w = t >> 6, l = t & 63;
    const int li = l & 15, lk = l >> 4;
    const int erow0 = w * 16;

    // epilogue metadata: lanes 0..15 hold this wave's 16 rows' src/dst
    int myS = 0, myD = 0;
    if (l < 16) {
        myS = srcd[e0 + erow0 + l];
        myD = dstd[e0 + erow0 + l];
    }

    // no barrier: frag reads are wave-local
    s16x8 Ah[2];
    #pragma unroll
    for (int s = 0; s < 2; ++s) {
        const int edge = erow0 + li;
        const int idx = (edge * ED + s * 32 + lk * 8) ^ ((edge & 7) << 3);
        Ah[s] = *(const s16x8*)&sAhi[idx];
    }
    __syncthreads();   // barrier A: staging dead across all waves; LDS becomes sM

    // ---- GEMM: 8 col-tiles x 4 MFMA; fp16 msg -> swizzled LDS rows ----
    #pragma unroll
    for (int c = 0; c < 8; ++c) {
        const int col = c * 16 + li;
        f32x4 acc0 = {0.f, 0.f, 0.f, 0.f};
        #pragma unroll
        for (int s = 0; s < 2; ++s) {
            const s16x8 Bh = *(const s16x8*)&WThi[col * ED + s * 32 + lk * 8];
            const s16x8 Bl = *(const s16x8*)&WTlo[col * ED + s * 32 + lk * 8];
            acc0 = MFMA16(Ah[s], Bh, acc0, 0, 0, 0);
            acc0 = MFMA16(Ah[s], Bl, acc0, 0, 0, 0);
        }
        const float bias = be[col];
        // D map [m89-verified]: col = lane&15, row = (lane>>4)*4 + reg
        #pragma unroll
        for (int reg = 0; reg < 4; ++reg) {
            const int r0 = erow0 + lk * 4 + reg;
            sM[(r0 * 128 + col) ^ ((r0 & 7) << 3)] = __float2half(acc0[reg] + bias);
        }
    }
    __syncthreads();   // barrier B: LOAD-BEARING (r17) - epilogue atomics out of GEMM

    // ---- segmented reduce (pure-atomic): wave owns 16 rows, lane owns 2 cols ----
    {
        const int c0 = l * 2;
        const int rbase = erow0;
        float2 acc = make_float2(0.f, 0.f);
        int cur = __shfl(myD, 0);

        unsigned int xA0, xA1, xA2, xA3, xA4, xA5, xA6, xA7;
        unsigned int xB0, xB1, xB2, xB3, xB4, xB5, xB6, xB7;

#define LOADG(d0,d1,d2,d3,d4,d5,d6,d7, g)                                          \
        do {                                                                       \
            d0 = *(const unsigned int*)&xbf[(size_t)__shfl(myS,(g)*8+0) * D + c0]; \
            d1 = *(const unsigned int*)&xbf[(size_t)__shfl(myS,(g)*8+1) * D + c0]; \
            d2 = *(const unsigned int*)&xbf[(size_t)__shfl(myS,(g)*8+2) * D + c0]; \
            d3 = *(const unsigned int*)&xbf[(size_t)__shfl(myS,(g)*8+3) * D + c0]; \
            d4 = *(const unsigned int*)&xbf[(size_t)__shfl(myS,(g)*8+4) * D + c0]; \
            d5 = *(const unsigned int*)&xbf[(size_t)__shfl(myS,(g)*8+5) * D + c0]; \
            d6 = *(const unsigned int*)&xbf[(size_t)__shfl(myS,(g)*8+6) * D + c0]; \
            d7 = *(const unsigned int*)&xbf[(size_t)__shfl(myS,(g)*8+7) * D + c0]; \
        } while (0)

#define PROC1(xu, rr)                                                              \
        do {                                                                       \
            const int row = rbase + (rr);                                          \
            const int dr = __shfl(myD, (rr));                                      \
            if (dr != cur) {                                                       \
                atomicAdd(&hpre[(size_t)cur * D + c0], acc.x);                     \
                atomicAdd(&hpre[(size_t)cur * D + c0 + 1], acc.y);                 \
                acc = make_float2(0.f, 0.f);                                       \
                cur = dr;                                                          \
            }                                                                      \
            float2 m = __half22float2(                                             \
                *(const __half2*)&sM[(row * 128 + c0) ^ ((row & 7) << 3)]);        \
            float xvx = bf2f((unsigned short)((xu) & 0xFFFFu));                    \
            float xvy = bf2f((unsigned short)((xu) >> 16));                        \
            acc.x += fmaxf(m.x + xvx, 0.f);                                        \
            acc.y += fmaxf(m.y + xvy, 0.f);                                        \
        } while (0)

        LOADG(xA0,xA1,xA2,xA3,xA4,xA5,xA6,xA7, 0);
        LOADG(xB0,xB1,xB2,xB3,xB4,xB5,xB6,xB7, 1);
        PROC1(xA0, 0); PROC1(xA1, 1); PROC1(xA2, 2); PROC1(xA3, 3);
        PROC1(xA4, 4); PROC1(xA5, 5); PROC1(xA6, 6); PROC1(xA7, 7);
        PROC1(xB0, 8); PROC1(xB1, 9); PROC1(xB2,10); PROC1(xB3,11);
        PROC1(xB4,12); PROC1(xB5,13); PROC1(xB6,14); PROC1(xB7,15);

        atomicAdd(&hpre[(size_t)cur * D + c0], acc.x);
        atomicAdd(&hpre[(size_t)cur * D + c0 + 1], acc.y);
#undef LOADG
#undef PROC1
    }
}

// ---------------- fused MLP pair, 32-row blocks (r23 config, unchanged) ----------------

__global__ __launch_bounds__(256, 6)
void mlp2_kernel(const float* __restrict__ in,
                 const unsigned short* __restrict__ W1h, const unsigned short* __restrict__ W1l,
                 const float* __restrict__ b1,
                 const unsigned short* __restrict__ W2h, const unsigned short* __restrict__ W2l,
                 const float* __restrict__ b2,
                 float* __restrict__ out, int relu2,
                 unsigned short* __restrict__ xbf_out)
{
    __shared__ unsigned short sHi[32 * D];   // 8192 B, swizzled rows
    __shared__ unsigned short sLo[32 * D];   // 8192 B
    const int t = threadIdx.x;
    const int n0 = blockIdx.x * 32;

    {
        const int r = t >> 3, k0 = (t & 7) * 16;
        const int gr = n0 + r;
        const int swz = (r & 7) << 3;
        #pragma unroll
        for (int j = 0; j < 2; ++j) {
            s16x8 vh = {0,0,0,0,0,0,0,0}, vl = {0,0,0,0,0,0,0,0};
            if (gr < N_NODES) {
                const float4* s4 = (const float4*)&in[(size_t)gr * D + k0 + j * 8];
                float4 va = s4[0], vb = s4[1];
                float f[8] = {va.x, va.y, va.z, va.w, vb.x, vb.y, vb.z, vb.w};
                #pragma unroll
                for (int q = 0; q < 8; ++q) {
                    unsigned short h = f2bf(f[q]);
                    vh[q] = (short)h;
                    vl[q] = (short)f2bf(f[q] - bf2f(h));
                }
            }
            *(s16x8*)&sHi[(r * D + k0 + j * 8) ^ swz] = vh;
            *(s16x8*)&sLo[(r * D + k0 + j * 8) ^ swz] = vl;
        }
    }
    __syncthreads();

    const int w = t >> 6, l = t & 63;
    const int li = l & 15, lk = l >> 4;
    const int rw0 = (w & 1) * 16;
    const int cw0 = (w >> 1) * 64;

    s16x8 Ah[4], Al[4];
    #pragma unroll
    for (int s = 0; s < 4; ++s) {
        const int row = rw0 + li;
        const int idx = (row * D + s * 32 + lk * 8) ^ ((row & 7) << 3);
        Ah[s] = *(const s16x8*)&sHi[idx];
        Al[s] = *(const s16x8*)&sLo[idx];
    }
    __syncthreads();

    #pragma unroll
    for (int c = 0; c < 4; ++c) {
        const int col = cw0 + c * 16 + li;
        f32x4 acc = {0.f, 0.f, 0.f, 0.f};
        #pragma unroll
        for (int s = 0; s < 4; ++s) {
            const s16x8 Bh = *(const s16x8*)&W1h[col * D + s * 32 + lk * 8];
            const s16x8 Bl = *(const s16x8*)&W1l[col * D + s * 32 + lk * 8];
            acc = MFMA16(Ah[s], Bh, acc, 0, 0, 0);
            acc = MFMA16(Ah[s], Bl, acc, 0, 0, 0);
            acc = MFMA16(Al[s], Bh, acc, 0, 0, 0);
        }
        const float bb = b1[col];
        #pragma unroll
        for (int reg = 0; reg < 4; ++reg) {
            const int row = rw0 + lk * 4 + reg;
            float v = fmaxf(acc[reg] + bb, 0.f);
            const int idx = (row * D + col) ^ ((row & 7) << 3);
            sHi[idx] = f2bf(v);
        }
    }
    __syncthreads();

    s16x8 Ch[4];
    #pragma unroll
    for (int s = 0; s < 4; ++s) {
        const int row = rw0 + li;
        const int idx = (row * D + s * 32 + lk * 8) ^ ((row & 7) << 3);
        Ch[s] = *(const s16x8*)&sHi[idx];
    }

    #pragma unroll
    for (int c = 0; c < 4; ++c) {
        const int col = cw0 + c * 16 + li;
        f32x4 acc = {0.f, 0.f, 0.f, 0.f};
        #pragma unroll
        for (int s = 0; s < 4; ++s) {
            const s16x8 Bh = *(const s16x8*)&W2h[col * D + s * 32 + lk * 8];
            const s16x8 Bl = *(const s16x8*)&W2l[col * D + s * 32 + lk * 8];
            acc = MFMA16(Ch[s], Bh, acc, 0, 0, 0);
            acc = MFMA16(Ch[s], Bl, acc, 0, 0, 0);
        }
        const float bb = b2[col];
        #pragma unroll
        for (int reg = 0; reg < 4; ++reg) {
            const int gr = n0 + rw0 + lk * 4 + reg;
            if (gr < N_NODES) {
                float v = acc[reg] + bb;
                if (relu2) v = fmaxf(v, 0.f);
                out[(size_t)gr * D + col] = v;
                if (xbf_out) xbf_out[(size_t)gr * D + col] = f2bf(v);
            }
        }
    }
}

// ---------------- host ----------------

extern "C" void kernel_launch(void* const* d_in, const int* in_sizes, int n_in,
                              void* d_out, int out_size, void* d_ws, size_t ws_size,
                              hipStream_t stream) {
    const float* x  = (const float*)d_in[0];
    const int*   ei = (const int*)d_in[1];
    const float* ea = (const float*)d_in[2];
    const float* We = (const float*)d_in[3];
    const float* be = (const float*)d_in[4];
    const float* W1 = (const float*)d_in[5];
    const float* b1 = (const float*)d_in[6];
    const float* W2 = (const float*)d_in[7];
    const float* b2 = (const float*)d_in[8];
    float* out = (float*)d_out;

    const int* src = ei;
    const int* dst = ei + N_EDGES;

    char* ws = (char*)d_ws;
    size_t off = 0;
    auto alloc = [&](size_t bytes) -> char* {
        char* p = ws + off;
        off = (off + bytes + 255) & ~(size_t)255;
        return p;
    };
    float* P          = (float*)alloc((size_t)N_NODES * D * 4);
    unsigned short* xbf = (unsigned short*)alloc((size_t)N_NODES * D * 2);
    int*   deg        = (int*)alloc((size_t)N_NODES * 4);
    int*   cursor     = (int*)alloc((size_t)N_NODES * 4);
    int*   bsum       = (int*)alloc((size_t)SCAN_NB * 4);
    int*   srcd       = (int*)alloc((size_t)N_EDGES * 4);
    int*   dstd       = (int*)alloc((size_t)N_EDGES * 4);
    unsigned short* WeThi = (unsigned short*)alloc((size_t)NLAYERS * D * ED * 2);
    unsigned short* WeTlo = (unsigned short*)alloc((size_t)NLAYERS * D * ED * 2);
    unsigned short* W1Thi = (unsigned short*)alloc((size_t)NLAYERS * D * D * 2);
    unsigned short* W1Tlo = (unsigned short*)alloc((size_t)NLAYERS * D * D * 2);
    unsigned short* W2Thi = (unsigned short*)alloc((size_t)NLAYERS * D * D * 2);
    unsigned short* W2Tlo = (unsigned short*)alloc((size_t)NLAYERS * D * D * 2);
    unsigned short* eahi = (unsigned short*)alloc((size_t)N_EDGES * ED * 2);
    (void)in_sizes; (void)n_in; (void)out_size; (void)ws_size;

    hipMemsetAsync(deg, 0, N_NODES * 4, stream);
    hist_kernel<<<(N_EDGES + 255) / 256, 256, 0, stream>>>(dst, deg);
    scan1_kernel<<<SCAN_NB, 256, 0, stream>>>(deg, cursor, bsum);
    scan2_kernel<<<1, 64, 0, stream>>>(bsum);
    scan3_kernel<<<SCAN_NB, 256, 0, stream>>>(cursor, bsum);
    reorder_fused_kernel<<<(N_EDGES * 4 + 255) / 256, 256, 0, stream>>>(
        (const float4*)ea, src, dst, cursor, eahi, srcd, dstd);
    wconvT_kernel<<<(NLAYERS * ED * D + 255) / 256, 256, 0, stream>>>(We, WeThi, WeTlo, NLAYERS, ED, D);
    wconvT_kernel<<<(NLAYERS * D * D + 255) / 256, 256, 0, stream>>>(W1, W1Thi, W1Tlo, NLAYERS, D, D);
    wconvT_kernel<<<(NLAYERS * D * D + 255) / 256, 256, 0, stream>>>(W2, W2Thi, W2Tlo, NLAYERS, D, D);

    const int mgrid = (N_NODES + 31) / 32;       // 1563

    // layer 0: P = x (fp32 seed) and xbf = bf16(x), single pass
    seed_kernel<<<(N_NODES * D / 8 + 255) / 256, 256, 0, stream>>>(x, P, xbf);

    for (int l = 0; l < NLAYERS; ++l) {
        const float* bel = be + (size_t)l * D;
        edge_fused_kernel<1><<<GGRID, 256, 0, stream>>>(xbf, eahi,
            srcd, dstd, WeThi + (size_t)l * D * ED, WeTlo + (size_t)l * D * ED, bel, P);
        if (l < NLAYERS - 1) {
            mlp2_kernel<<<mgrid, 256, 0, stream>>>(P,
                W1Thi + (size_t)l * D * D, W1Tlo + (size_t)l * D * D, b1 + (size_t)l * D,
                W2Thi + (size_t)l * D * D, W2Tlo + (size_t)l * D * D, b2 + (size_t)l * D,
                P, 1, xbf);
        } else {
            mlp2_kernel<<<mgrid, 256, 0, stream>>>(P,
                W1Thi + (size_t)l * D * D, W1Tlo + (size_t)l * D * D, b1 + (size_t)l * D,
                W2Thi + (size_t)l * D * D, W2Tlo + (size_t)l * D * D, b2 + (size_t)l * D,
                out, 0, nullptr);
        }
    }
}

// Round 26
// 661.056 us; speedup vs baseline: 1.4157x; 1.4157x over previous
//
#include <hip/hip_runtime.h>
#include <hip/hip_fp16.h>

#define N_NODES 50000
#define N_EDGES 800000
#define D 128
#define ED 64
#define NLAYERS 3

typedef __attribute__((ext_vector_type(8))) short s16x8;
typedef __attribute__((ext_vector_type(4))) float f32x4;
#define MFMA16 __builtin_amdgcn_mfma_f32_16x16x32_bf16

__device__ __forceinline__ unsigned short f2bf(float f) {
    unsigned int u = __float_as_uint(f);
    unsigned int r = (u + 0x7FFFu + ((u >> 16) & 1u)) >> 16;
    return (unsigned short)r;
}
__device__ __forceinline__ float bf2f(unsigned short h) {
    return __uint_as_float(((unsigned int)h) << 16);
}

// ---------------- prep kernels ----------------

__global__ void hist_kernel(const int* __restrict__ dst, int* __restrict__ deg) {
    int e = blockIdx.x * blockDim.x + threadIdx.x;
    if (e < N_EDGES) atomicAdd(&deg[dst[e]], 1);
}

// parallel exclusive scan of deg -> cursor (3 phases)
#define SCAN_NB ((N_NODES + 255) / 256)   // 196

__global__ void scan1_kernel(const int* __restrict__ deg, int* __restrict__ curs,
                             int* __restrict__ bsum) {
    __shared__ int wtot[4];
    const int i = blockIdx.x * 256 + threadIdx.x;
    const int l = threadIdx.x & 63, w = threadIdx.x >> 6;
    int v = (i < N_NODES) ? deg[i] : 0;
    int s = v;
    #pragma unroll
    for (int off = 1; off < 64; off <<= 1) {
        int y = __shfl_up(s, off);
        if (l >= off) s += y;
    }
    if (l == 63) wtot[w] = s;
    __syncthreads();
    int add = 0;
    #pragma unroll
    for (int ww = 0; ww < 4; ++ww) if (ww < w) add += wtot[ww];
    if (i < N_NODES) curs[i] = add + s - v;
    if (threadIdx.x == 255) bsum[blockIdx.x] = add + s;
}

__global__ void scan2_kernel(int* __restrict__ bsum) {   // 1 block, 64 threads
    const int l = threadIdx.x;
    int acc = 0;
    for (int base = 0; base < SCAN_NB; base += 64) {
        int v = (base + l < SCAN_NB) ? bsum[base + l] : 0;
        int s = v;
        #pragma unroll
        for (int off = 1; off < 64; off <<= 1) {
            int y = __shfl_up(s, off);
            if (l >= off) s += y;
        }
        if (base + l < SCAN_NB) bsum[base + l] = acc + s - v;
        acc += __shfl(s, 63);
    }
}

__global__ void scan3_kernel(int* __restrict__ curs, const int* __restrict__ bsum) {
    int i = blockIdx.x * 256 + threadIdx.x;
    if (i < N_NODES) curs[i] += bsum[blockIdx.x];
}

// FUSED scatter+reorder: sequential ea read, bf16-hi convert, random write at
// sorted position (atomic cursor). A-lo dropped (r21-validated).
__global__ void reorder_fused_kernel(const float4* __restrict__ ea,
                                     const int* __restrict__ src, const int* __restrict__ dst,
                                     int* __restrict__ cursor,
                                     unsigned short* __restrict__ eahi,
                                     int* __restrict__ srcd, int* __restrict__ dstd) {
    int idx = blockIdx.x * blockDim.x + threadIdx.x;
    int i = idx >> 2, q = idx & 3;     // 4 lanes per edge
    if (i >= N_EDGES) return;
    const int l = threadIdx.x & 63;
    int pos = 0;
    if (q == 0) pos = atomicAdd(&cursor[dst[i]], 1);
    pos = __shfl(pos, (l >> 2) << 2);

    const float4* srow = ea + (size_t)i * (ED / 4) + q * 4;
    float f[16];
    #pragma unroll
    for (int j = 0; j < 4; ++j) {
        float4 v = srow[j];
        f[j * 4 + 0] = v.x; f[j * 4 + 1] = v.y; f[j * 4 + 2] = v.z; f[j * 4 + 3] = v.w;
    }
    s16x8 h0, h1;
    #pragma unroll
    for (int j = 0; j < 8; ++j) h0[j] = (short)f2bf(f[j]);
    #pragma unroll
    for (int j = 0; j < 8; ++j) h1[j] = (short)f2bf(f[8 + j]);
    size_t o = (size_t)pos * ED + q * 16;
    *(s16x8*)&eahi[o] = h0; *(s16x8*)&eahi[o + 8] = h1;
    if (q == 0) { srcd[pos] = src[i]; dstd[pos] = dst[i]; }
}

// Wsrc[L][K][C] -> transposed bf16 hi/lo T[L][C][K]
__global__ void wconvT_kernel(const float* __restrict__ Wsrc,
                              unsigned short* __restrict__ Thi,
                              unsigned short* __restrict__ Tlo,
                              int L, int K, int C) {
    int idx = blockIdx.x * 256 + threadIdx.x;
    if (idx < L * K * C) {
        int l = idx / (K * C);
        int rem = idx % (K * C);
        int k = rem / C, c = rem % C;
        float f = Wsrc[idx];
        unsigned short h = f2bf(f);
        unsigned short lo = f2bf(f - bf2f(h));
        int o = (l * C + c) * K + k;
        Thi[o] = h; Tlo[o] = lo;
    }
}

// seed: P = x (fp32 copy) and xbf = bf16(x), one read pass
__global__ void seed_kernel(const float* __restrict__ xin, float* __restrict__ P,
                            unsigned short* __restrict__ xbf) {
    int idx = blockIdx.x * 256 + threadIdx.x;   // 8 elems per thread
    if (idx < N_NODES * D / 8) {
        const float4* s = (const float4*)xin + (size_t)idx * 2;
        float4 a = s[0], b = s[1];
        float4* p = (float4*)P + (size_t)idx * 2;
        p[0] = a; p[1] = b;
        float f[8] = {a.x, a.y, a.z, a.w, b.x, b.y, b.z, b.w};
        s16x8 h;
        #pragma unroll
        for (int j = 0; j < 8; ++j) h[j] = (short)f2bf(f[j]);
        *(s16x8*)&xbf[(size_t)idx * 8] = h;
    }
}

// ---------------- fused edge pass (r24 best config: 128-edge tiles) ----------------
// 128 dst-sorted edges/block, 4 waves, LDS 32 KB (msg tile; 16 KB staging
// aliased) -> 5 blocks/CU. Wave-local staging (no stage barrier); barrier A
// (sM alias) + barrier B (r17, pre-epilogue). r25 showed smaller tiles lose
// (boundary-atomic + gather duplication outweighs occupancy).

#define GGRID (N_EDGES / 128)      // 6250
#define XQ (GGRID / 8)             // 781
#define XR (GGRID % 8)             // 2

template<int DIRECT>
__global__ __launch_bounds__(256, 5)
void edge_fused_kernel(const unsigned short* __restrict__ xbf,
                       const unsigned short* __restrict__ eahi,
                       const int* __restrict__ srcd,
                       const int* __restrict__ dstd,
                       const unsigned short* __restrict__ WThi,
                       const unsigned short* __restrict__ WTlo,
                       const float* __restrict__ be,
                       float* __restrict__ hpre)
{
    __shared__ __half sM[128 * 128];                 // 32768 B (msg tile, swizzled)
    unsigned short* sAhi = (unsigned short*)sM;      // 16 KB staging aliased at base

    const int t = threadIdx.x;
    const int bid = blockIdx.x;
    const int xcd = bid & 7, jj = bid >> 3;
    const int blk = (xcd < XR ? xcd * (XQ + 1) : XR * (XQ + 1) + (xcd - XR) * XQ) + jj;
    const int e0 = blk * 128;

    // ---- stage (hi only; wave-local rows) ----
    {
        const int el = t >> 1, k0 = (t & 1) * 32;
        const int swz = (el & 7) << 3;
        const size_t gb = (size_t)(e0 + el) * ED + k0;
        #pragma unroll
        for (int j = 0; j < 4; ++j) {
            s16x8 vh = *(const s16x8*)&eahi[gb + j * 8];
            *(s16x8*)&sAhi[(el * ED + k0 + j * 8) ^ swz] = vh;
        }
    }

    const int w = t >> 6, l = t & 63;
    const int li = l & 15, lk = l >> 4;
    const int erow0 = w * 32;

    // epilogue metadata: lanes 0..31 load this wave's 32 rows' src/dst
    int myS = 0, myD = 0;
    if (l < 32) {
        myS = srcd[e0 + erow0 + l];
        myD = dstd[e0 + erow0 + l];
    }

    // no barrier: frag reads are wave-local (same rows this wave staged)
    s16x8 Ah[2][2];
    #pragma unroll
    for (int r = 0; r < 2; ++r)
        #pragma unroll
        for (int s = 0; s < 2; ++s) {
            const int edge = erow0 + r * 16 + li;
            const int idx = (edge * ED + s * 32 + lk * 8) ^ ((edge & 7) << 3);
            Ah[r][s] = *(const s16x8*)&sAhi[idx];
        }
    __syncthreads();   // barrier A: staging dead across ALL waves; LDS becomes sM

    #pragma unroll
    for (int c = 0; c < 8; ++c) {
        const int col = c * 16 + li;
        f32x4 acc0 = {0.f, 0.f, 0.f, 0.f}, acc1 = {0.f, 0.f, 0.f, 0.f};
        #pragma unroll
        for (int s = 0; s < 2; ++s) {
            const s16x8 Bh = *(const s16x8*)&WThi[col * ED + s * 32 + lk * 8];
            const s16x8 Bl = *(const s16x8*)&WTlo[col * ED + s * 32 + lk * 8];
            acc0 = MFMA16(Ah[0][s], Bh, acc0, 0, 0, 0);
            acc1 = MFMA16(Ah[1][s], Bh, acc1, 0, 0, 0);
            acc0 = MFMA16(Ah[0][s], Bl, acc0, 0, 0, 0);
            acc1 = MFMA16(Ah[1][s], Bl, acc1, 0, 0, 0);
        }
        const float bias = be[col];
        // D map [m89-verified]: col = lane&15, row = (lane>>4)*4 + reg
        #pragma unroll
        for (int reg = 0; reg < 4; ++reg) {
            const int r0 = erow0 + lk * 4 + reg;
            const int r1 = r0 + 16;
            sM[(r0 * 128 + col) ^ ((r0 & 7) << 3)] = __float2half(acc0[reg] + bias);
            sM[(r1 * 128 + col) ^ ((r1 & 7) << 3)] = __float2half(acc1[reg] + bias);
        }
    }
    __syncthreads();   // barrier B: LOAD-BEARING (r17) - epilogue atomics out of GEMM

    // ---- segmented reduce (pure-atomic) ----
    {
        const int c0 = l * 2;
        const int rbase = erow0;
        float2 acc = make_float2(0.f, 0.f);
        int cur = __shfl(myD, 0);

        unsigned int xA0, xA1, xA2, xA3, xA4, xA5, xA6, xA7;
        unsigned int xB0, xB1, xB2, xB3, xB4, xB5, xB6, xB7;

#define LOADG(d0,d1,d2,d3,d4,d5,d6,d7, g)                                          \
        do {                                                                       \
            d0 = *(const unsigned int*)&xbf[(size_t)__shfl(myS,(g)*8+0) * D + c0]; \
            d1 = *(const unsigned int*)&xbf[(size_t)__shfl(myS,(g)*8+1) * D + c0]; \
            d2 = *(const unsigned int*)&xbf[(size_t)__shfl(myS,(g)*8+2) * D + c0]; \
            d3 = *(const unsigned int*)&xbf[(size_t)__shfl(myS,(g)*8+3) * D + c0]; \
            d4 = *(const unsigned int*)&xbf[(size_t)__shfl(myS,(g)*8+4) * D + c0]; \
            d5 = *(const unsigned int*)&xbf[(size_t)__shfl(myS,(g)*8+5) * D + c0]; \
            d6 = *(const unsigned int*)&xbf[(size_t)__shfl(myS,(g)*8+6) * D + c0]; \
            d7 = *(const unsigned int*)&xbf[(size_t)__shfl(myS,(g)*8+7) * D + c0]; \
        } while (0)

#define PROC1(xu, rr)                                                              \
        do {                                                                       \
            const int row = rbase + (rr);                                          \
            const int dr = __shfl(myD, (rr));                                      \
            if (dr != cur) {                                                       \
                atomicAdd(&hpre[(size_t)cur * D + c0], acc.x);                     \
                atomicAdd(&hpre[(size_t)cur * D + c0 + 1], acc.y);                 \
                acc = make_float2(0.f, 0.f);                                       \
                cur = dr;                                                          \
            }                                                                      \
            float2 m = __half22float2(                                             \
                *(const __half2*)&sM[(row * 128 + c0) ^ ((row & 7) << 3)]);        \
            float xvx = bf2f((unsigned short)((xu) & 0xFFFFu));                    \
            float xvy = bf2f((unsigned short)((xu) >> 16));                        \
            acc.x += fmaxf(m.x + xvx, 0.f);                                        \
            acc.y += fmaxf(m.y + xvy, 0.f);                                        \
        } while (0)

        LOADG(xA0,xA1,xA2,xA3,xA4,xA5,xA6,xA7, 0);
        LOADG(xB0,xB1,xB2,xB3,xB4,xB5,xB6,xB7, 1);
        PROC1(xA0, 0); PROC1(xA1, 1); PROC1(xA2, 2); PROC1(xA3, 3);
        PROC1(xA4, 4); PROC1(xA5, 5); PROC1(xA6, 6); PROC1(xA7, 7);
        LOADG(xA0,xA1,xA2,xA3,xA4,xA5,xA6,xA7, 2);
        PROC1(xB0, 8); PROC1(xB1, 9); PROC1(xB2,10); PROC1(xB3,11);
        PROC1(xB4,12); PROC1(xB5,13); PROC1(xB6,14); PROC1(xB7,15);
        LOADG(xB0,xB1,xB2,xB3,xB4,xB5,xB6,xB7, 3);
        PROC1(xA0,16); PROC1(xA1,17); PROC1(xA2,18); PROC1(xA3,19);
        PROC1(xA4,20); PROC1(xA5,21); PROC1(xA6,22); PROC1(xA7,23);
        PROC1(xB0,24); PROC1(xB1,25); PROC1(xB2,26); PROC1(xB3,27);
        PROC1(xB4,28); PROC1(xB5,29); PROC1(xB6,30); PROC1(xB7,31);

        atomicAdd(&hpre[(size_t)cur * D + c0], acc.x);
        atomicAdd(&hpre[(size_t)cur * D + c0 + 1], acc.y);
#undef LOADG
#undef PROC1
    }
}

// ---------------- fused MLP pair, 32-row blocks ----------------

__global__ __launch_bounds__(256, 6)
void mlp2_kernel(const float* __restrict__ in,
                 const unsigned short* __restrict__ W1h, const unsigned short* __restrict__ W1l,
                 const float* __restrict__ b1,
                 const unsigned short* __restrict__ W2h, const unsigned short* __restrict__ W2l,
                 const float* __restrict__ b2,
                 float* __restrict__ out, int relu2,
                 unsigned short* __restrict__ xbf_out)
{
    __shared__ unsigned short sHi[32 * D];   // 8192 B, swizzled rows
    __shared__ unsigned short sLo[32 * D];   // 8192 B
    const int t = threadIdx.x;
    const int n0 = blockIdx.x * 32;

    {
        const int r = t >> 3, k0 = (t & 7) * 16;
        const int gr = n0 + r;
        const int swz = (r & 7) << 3;
        #pragma unroll
        for (int j = 0; j < 2; ++j) {
            s16x8 vh = {0,0,0,0,0,0,0,0}, vl = {0,0,0,0,0,0,0,0};
            if (gr < N_NODES) {
                const float4* s4 = (const float4*)&in[(size_t)gr * D + k0 + j * 8];
                float4 va = s4[0], vb = s4[1];
                float f[8] = {va.x, va.y, va.z, va.w, vb.x, vb.y, vb.z, vb.w};
                #pragma unroll
                for (int q = 0; q < 8; ++q) {
                    unsigned short h = f2bf(f[q]);
                    vh[q] = (short)h;
                    vl[q] = (short)f2bf(f[q] - bf2f(h));
                }
            }
            *(s16x8*)&sHi[(r * D + k0 + j * 8) ^ swz] = vh;
            *(s16x8*)&sLo[(r * D + k0 + j * 8) ^ swz] = vl;
        }
    }
    __syncthreads();

    const int w = t >> 6, l = t & 63;
    const int li = l & 15, lk = l >> 4;
    const int rw0 = (w & 1) * 16;
    const int cw0 = (w >> 1) * 64;

    s16x8 Ah[4], Al[4];
    #pragma unroll
    for (int s = 0; s < 4; ++s) {
        const int row = rw0 + li;
        const int idx = (row * D + s * 32 + lk * 8) ^ ((row & 7) << 3);
        Ah[s] = *(const s16x8*)&sHi[idx];
        Al[s] = *(const s16x8*)&sLo[idx];
    }
    __syncthreads();

    #pragma unroll
    for (int c = 0; c < 4; ++c) {
        const int col = cw0 + c * 16 + li;
        f32x4 acc = {0.f, 0.f, 0.f, 0.f};
        #pragma unroll
        for (int s = 0; s < 4; ++s) {
            const s16x8 Bh = *(const s16x8*)&W1h[col * D + s * 32 + lk * 8];
            const s16x8 Bl = *(const s16x8*)&W1l[col * D + s * 32 + lk * 8];
            acc = MFMA16(Ah[s], Bh, acc, 0, 0, 0);
            acc = MFMA16(Ah[s], Bl, acc, 0, 0, 0);
            acc = MFMA16(Al[s], Bh, acc, 0, 0, 0);
        }
        const float bb = b1[col];
        #pragma unroll
        for (int reg = 0; reg < 4; ++reg) {
            const int row = rw0 + lk * 4 + reg;
            float v = fmaxf(acc[reg] + bb, 0.f);
            const int idx = (row * D + col) ^ ((row & 7) << 3);
            sHi[idx] = f2bf(v);
        }
    }
    __syncthreads();

    s16x8 Ch[4];
    #pragma unroll
    for (int s = 0; s < 4; ++s) {
        const int row = rw0 + li;
        const int idx = (row * D + s * 32 + lk * 8) ^ ((row & 7) << 3);
        Ch[s] = *(const s16x8*)&sHi[idx];
    }

    #pragma unroll
    for (int c = 0; c < 4; ++c) {
        const int col = cw0 + c * 16 + li;
        f32x4 acc = {0.f, 0.f, 0.f, 0.f};
        #pragma unroll
        for (int s = 0; s < 4; ++s) {
            const s16x8 Bh = *(const s16x8*)&W2h[col * D + s * 32 + lk * 8];
            const s16x8 Bl = *(const s16x8*)&W2l[col * D + s * 32 + lk * 8];
            acc = MFMA16(Ch[s], Bh, acc, 0, 0, 0);
            acc = MFMA16(Ch[s], Bl, acc, 0, 0, 0);
        }
        const float bb = b2[col];
        #pragma unroll
        for (int reg = 0; reg < 4; ++reg) {
            const int gr = n0 + rw0 + lk * 4 + reg;
            if (gr < N_NODES) {
                float v = acc[reg] + bb;
                if (relu2) v = fmaxf(v, 0.f);
                out[(size_t)gr * D + col] = v;
                if (xbf_out) xbf_out[(size_t)gr * D + col] = f2bf(v);
            }
        }
    }
}

// ---------------- host ----------------

extern "C" void kernel_launch(void* const* d_in, const int* in_sizes, int n_in,
                              void* d_out, int out_size, void* d_ws, size_t ws_size,
                              hipStream_t stream) {
    const float* x  = (const float*)d_in[0];
    const int*   ei = (const int*)d_in[1];
    const float* ea = (const float*)d_in[2];
    const float* We = (const float*)d_in[3];
    const float* be = (const float*)d_in[4];
    const float* W1 = (const float*)d_in[5];
    const float* b1 = (const float*)d_in[6];
    const float* W2 = (const float*)d_in[7];
    const float* b2 = (const float*)d_in[8];
    float* out = (float*)d_out;

    const int* src = ei;
    const int* dst = ei + N_EDGES;

    char* ws = (char*)d_ws;
    size_t off = 0;
    auto alloc = [&](size_t bytes) -> char* {
        char* p = ws + off;
        off = (off + bytes + 255) & ~(size_t)255;
        return p;
    };
    float* P          = (float*)alloc((size_t)N_NODES * D * 4);
    unsigned short* xbf = (unsigned short*)alloc((size_t)N_NODES * D * 2);
    int*   deg        = (int*)alloc((size_t)N_NODES * 4);
    int*   cursor     = (int*)alloc((size_t)N_NODES * 4);
    int*   bsum       = (int*)alloc((size_t)SCAN_NB * 4);
    int*   srcd       = (int*)alloc((size_t)N_EDGES * 4);
    int*   dstd       = (int*)alloc((size_t)N_EDGES * 4);
    unsigned short* WeThi = (unsigned short*)alloc((size_t)NLAYERS * D * ED * 2);
    unsigned short* WeTlo = (unsigned short*)alloc((size_t)NLAYERS * D * ED * 2);
    unsigned short* W1Thi = (unsigned short*)alloc((size_t)NLAYERS * D * D * 2);
    unsigned short* W1Tlo = (unsigned short*)alloc((size_t)NLAYERS * D * D * 2);
    unsigned short* W2Thi = (unsigned short*)alloc((size_t)NLAYERS * D * D * 2);
    unsigned short* W2Tlo = (unsigned short*)alloc((size_t)NLAYERS * D * D * 2);
    unsigned short* eahi = (unsigned short*)alloc((size_t)N_EDGES * ED * 2);
    (void)in_sizes; (void)n_in; (void)out_size; (void)ws_size;

    hipMemsetAsync(deg, 0, N_NODES * 4, stream);
    hist_kernel<<<(N_EDGES + 255) / 256, 256, 0, stream>>>(dst, deg);
    scan1_kernel<<<SCAN_NB, 256, 0, stream>>>(deg, cursor, bsum);
    scan2_kernel<<<1, 64, 0, stream>>>(bsum);
    scan3_kernel<<<SCAN_NB, 256, 0, stream>>>(cursor, bsum);
    reorder_fused_kernel<<<(N_EDGES * 4 + 255) / 256, 256, 0, stream>>>(
        (const float4*)ea, src, dst, cursor, eahi, srcd, dstd);
    wconvT_kernel<<<(NLAYERS * ED * D + 255) / 256, 256, 0, stream>>>(We, WeThi, WeTlo, NLAYERS, ED, D);
    wconvT_kernel<<<(NLAYERS * D * D + 255) / 256, 256, 0, stream>>>(W1, W1Thi, W1Tlo, NLAYERS, D, D);
    wconvT_kernel<<<(NLAYERS * D * D + 255) / 256, 256, 0, stream>>>(W2, W2Thi, W2Tlo, NLAYERS, D, D);

    const int mgrid = (N_NODES + 31) / 32;       // 1563

    // layer 0: P = x (fp32 seed) and xbf = bf16(x), single pass
    seed_kernel<<<(N_NODES * D / 8 + 255) / 256, 256, 0, stream>>>(x, P, xbf);

    for (int l = 0; l < NLAYERS; ++l) {
        const float* bel = be + (size_t)l * D;
        edge_fused_kernel<1><<<GGRID, 256, 0, stream>>>(xbf, eahi,
            srcd, dstd, WeThi + (size_t)l * D * ED, WeTlo + (size_t)l * D * ED, bel, P);
        if (l < NLAYERS - 1) {
            mlp2_kernel<<<mgrid, 256, 0, stream>>>(P,
                W1Thi + (size_t)l * D * D, W1Tlo + (size_t)l * D * D, b1 + (size_t)l * D,
                W2Thi + (size_t)l * D * D, W2Tlo + (size_t)l * D * D, b2 + (size_t)l * D,
                P, 1, xbf);
        } else {
            mlp2_kernel<<<mgrid, 256, 0, stream>>>(P,
                W1Thi + (size_t)l * D * D, W1Tlo + (size_t)l * D * D, b1 + (size_t)l * D,
                W2Thi + (size_t)l * D * D, W2Tlo + (size_t)l * D * D, b2 + (size_t)l * D,
                out, 0, nullptr);
        }
    }
}